// Round 1
// 217.362 us; speedup vs baseline: 1.0382x; 1.0382x over previous
//
#include <hip/hip_runtime.h>

#define NB 16
#define NC 256
#define NH 64
#define NW 64
#define PATCH 9
#define TROWS 4
#define CHST (NH * NW)               // channel plane stride (floats)
#define BLOCK_THREADS 192            // 3 waves; wave w handles di = 3*g + w

typedef float f4_vec __attribute__((ext_vector_type(4)));

// DPP 16-lane-row shifts. CDNA semantics:
//   row_shr:1 (0x111): lane l  <-  lane l-1   (first lane of row -> 0)
//   row_shl:1 (0x101): lane l  <-  lane l+1   (last  lane of row -> 0)
// Our 16-lane col-groups coincide exactly with DPP rows, so the shifted-in
// zeros implement the horizontal zero-padding of y for free.
__device__ __forceinline__ float from_prev_lane(float v) {  // lane l <- lane l-1
    return __int_as_float(__builtin_amdgcn_update_dpp(
        0, __float_as_int(v), 0x111, 0xF, 0xF, true));      // row_shr:1
}
__device__ __forceinline__ float from_next_lane(float v) {  // lane l <- lane l+1
    return __int_as_float(__builtin_amdgcn_update_dpp(
        0, __float_as_int(v), 0x101, 0xF, 0xF, true));      // row_shl:1
}

// out[b, di*9+dj, i, j] = (1/C) * sum_c x[b,c,i,j] * y[b,c,i+di-4, j+dj-4]
__global__ void __launch_bounds__(BLOCK_THREADS)
corr_kernel(const float* __restrict__ x, const float* __restrict__ y,
            float* __restrict__ out, const float* __restrict__ zpad)
{
    const int tid  = threadIdx.x;
    const int w    = tid >> 6;           // wave 0..2
    const int ln   = tid & 63;
    const int prow = ln >> 4;            // pixel row within tile (DPP-row index)
    const int j0   = (ln & 15) << 2;     // col base, lane order == col order

    // XCD-localizing bijective swizzle.
    // HW round-robins blockIdx across the 8 XCDs (XCD = blockIdx & 7), and
    // with 768 blocks the grid is exactly fully resident (3 blocks/CU), so
    // the mapping is stable. Pin each batch b's 48 blocks (3 di-triples x
    // 16 row-tiles) to ONE XCD (b = xcd, xcd+8) so the 12x-redundant x/y
    // row re-reads hit that XCD's 4 MiB L2 instead of flooding L3.
    // Within an XCD: t-major, with the 3 di-triple blocks of the same
    // (b,t) adjacent in dispatch order (keeps them c-synchronized).
    const int n    = blockIdx.x;
    const int xcd  = n & 7;
    int k          = n >> 3;             // 0..95 within XCD
    const int bsel = (k >= 48) ? 1 : 0;
    k -= 48 * bsel;
    const int b    = xcd + (bsel << 3);  // 2 batches per XCD
    const int t    = k / 3;              // row-tile 0..15
    const int g    = k - t * 3;          // di triple 0..2
    const int r0   = t * TROWS;

    const int di = g * 3 + w;            // 0..8, wave-uniform
    const int i  = r0 + prow;            // output pixel row
    const int yr = i + di - 4;           // y row this thread needs
    const bool rv = (yr >= 0) && (yr < NH);

    // x: always valid. y: invalid rows read a zeroed ws region with stride 0.
    const float* xp = x + ((size_t)(b * NC) * NH + i) * NW + j0;
    const float* yp = rv ? (y + ((size_t)(b * NC) * NH + yr) * NW + j0)
                         : (zpad + j0);
    const size_t ystep = rv ? (size_t)CHST : 0;

    float acc[PATCH][4];
    #pragma unroll
    for (int dj = 0; dj < PATCH; ++dj)
        #pragma unroll
        for (int tt = 0; tt < 4; ++tt) acc[dj][tt] = 0.0f;

    // depth-2 register prefetch pipeline (no LDS, no barriers)
    float4 xa = *(const float4*)(xp);
    float4 ya = *(const float4*)(yp);
    float4 xb = *(const float4*)(xp + CHST);
    float4 yb = *(const float4*)(yp + ystep);

    #pragma unroll 2
    for (int c = 0; c < NC; ++c) {
        const int cn = (c + 2 < NC) ? c + 2 : c;     // harmless tail reload
        float4 xn = *(const float4*)(xp + (size_t)cn * CHST);
        float4 yn = *(const float4*)(yp + (size_t)cn * ystep);

        // 12-float window [j0-4, j0+8): neighbors via DPP, edges auto-zero
        float wnd[12];
        wnd[0]  = from_prev_lane(ya.x);  wnd[1]  = from_prev_lane(ya.y);
        wnd[2]  = from_prev_lane(ya.z);  wnd[3]  = from_prev_lane(ya.w);
        wnd[4]  = ya.x;                  wnd[5]  = ya.y;
        wnd[6]  = ya.z;                  wnd[7]  = ya.w;
        wnd[8]  = from_next_lane(ya.x);  wnd[9]  = from_next_lane(ya.y);
        wnd[10] = from_next_lane(ya.z);  wnd[11] = from_next_lane(ya.w);

        const float xs[4] = {xa.x, xa.y, xa.z, xa.w};
        #pragma unroll
        for (int dj = 0; dj < PATCH; ++dj)
            #pragma unroll
            for (int tt = 0; tt < 4; ++tt)
                acc[dj][tt] = fmaf(xs[tt], wnd[tt + dj], acc[dj][tt]);

        xa = xb; xb = xn; ya = yb; yb = yn;
    }

    // epilogue: scale, coalesced nontemporal float4 stores (output is
    // write-once, never re-read -> keep it out of L2 so the live x/y
    // c-planes of same-XCD blocks stay resident).
    const float scale = 1.0f / (float)NC;
    float* op = out + (((size_t)b * (PATCH * PATCH) + di * PATCH) * NH + i) * NW + j0;
    #pragma unroll
    for (int dj = 0; dj < PATCH; ++dj) {
        f4_vec o;
        o.x = acc[dj][0] * scale; o.y = acc[dj][1] * scale;
        o.z = acc[dj][2] * scale; o.w = acc[dj][3] * scale;
        __builtin_nontemporal_store(o, (f4_vec*)(op + (size_t)dj * CHST));
    }
}

extern "C" void kernel_launch(void* const* d_in, const int* in_sizes, int n_in,
                              void* d_out, int out_size, void* d_ws, size_t ws_size,
                              hipStream_t stream)
{
    const float* x = (const float*)d_in[0];
    const float* y = (const float*)d_in[1];
    float* out = (float*)d_out;

    // zero page for out-of-range y rows (ws is re-poisoned every launch)
    hipMemsetAsync(d_ws, 0, 1024, stream);

    dim3 grid(3 * NB * (NH / TROWS));   // 768 = exactly 3 blocks/CU resident
    dim3 block(BLOCK_THREADS);          // 192 threads = 3 waves (no barriers used)
    hipLaunchKernelGGL(corr_kernel, grid, block, 0, stream, x, y, out,
                       (const float*)d_ws);
}

// Round 2
// 197.126 us; speedup vs baseline: 1.1447x; 1.1027x over previous
//
#include <hip/hip_runtime.h>

#define NB 16
#define NC 256
#define NH 64
#define NW 64
#define PATCH 9
#define TROWS 4
#define CHST (NH * NW)               // channel plane stride (floats)
#define BLOCK_THREADS 192            // 3 waves; wave w handles di = 3*g + w
#define DEPTH 8                      // software-pipeline depth (loads in flight = 2*DEPTH)

typedef float f4_vec __attribute__((ext_vector_type(4)));

// DPP 16-lane-row shifts. CDNA semantics:
//   row_shr:1 (0x111): lane l  <-  lane l-1   (first lane of row -> 0)
//   row_shl:1 (0x101): lane l  <-  lane l+1   (last  lane of row -> 0)
// Our 16-lane col-groups coincide exactly with DPP rows, so the shifted-in
// zeros implement the horizontal zero-padding of y for free.
__device__ __forceinline__ float from_prev_lane(float v) {  // lane l <- lane l-1
    return __int_as_float(__builtin_amdgcn_update_dpp(
        0, __float_as_int(v), 0x111, 0xF, 0xF, true));      // row_shr:1
}
__device__ __forceinline__ float from_next_lane(float v) {  // lane l <- lane l+1
    return __int_as_float(__builtin_amdgcn_update_dpp(
        0, __float_as_int(v), 0x101, 0xF, 0xF, true));      // row_shl:1
}

__device__ __forceinline__ void accum(float acc[PATCH][4], float4 xa, float4 ya) {
    // 12-float window [j0-4, j0+8): neighbors via DPP, edges auto-zero
    float wnd[12];
    wnd[0]  = from_prev_lane(ya.x);  wnd[1]  = from_prev_lane(ya.y);
    wnd[2]  = from_prev_lane(ya.z);  wnd[3]  = from_prev_lane(ya.w);
    wnd[4]  = ya.x;                  wnd[5]  = ya.y;
    wnd[6]  = ya.z;                  wnd[7]  = ya.w;
    wnd[8]  = from_next_lane(ya.x);  wnd[9]  = from_next_lane(ya.y);
    wnd[10] = from_next_lane(ya.z);  wnd[11] = from_next_lane(ya.w);

    const float xs[4] = {xa.x, xa.y, xa.z, xa.w};
    #pragma unroll
    for (int dj = 0; dj < PATCH; ++dj)
        #pragma unroll
        for (int tt = 0; tt < 4; ++tt)
            acc[dj][tt] = fmaf(xs[tt], wnd[tt + dj], acc[dj][tt]);
}

// out[b, di*9+dj, i, j] = (1/C) * sum_c x[b,c,i,j] * y[b,c,i+di-4, j+dj-4]
__global__ void __launch_bounds__(BLOCK_THREADS)
corr_kernel(const float* __restrict__ x, const float* __restrict__ y,
            float* __restrict__ out, const float* __restrict__ zpad)
{
    const int tid  = threadIdx.x;
    const int w    = tid >> 6;           // wave 0..2
    const int ln   = tid & 63;
    const int prow = ln >> 4;            // pixel row within tile (DPP-row index)
    const int j0   = (ln & 15) << 2;     // col base, lane order == col order

    // XCD-localizing bijective swizzle (neutral at 116 us, should matter as we
    // approach the aggregate L2 ceiling): pin each batch b's 48 blocks to one
    // XCD (b = xcd, xcd+8), t-major within, di-triples adjacent.
    const int n    = blockIdx.x;
    const int xcd  = n & 7;
    int k          = n >> 3;             // 0..95 within XCD
    const int bsel = (k >= 48) ? 1 : 0;
    k -= 48 * bsel;
    const int b    = xcd + (bsel << 3);  // 2 batches per XCD
    const int t    = k / 3;              // row-tile 0..15
    const int g    = k - t * 3;          // di triple 0..2
    const int r0   = t * TROWS;

    const int di = g * 3 + w;            // 0..8, wave-uniform
    const int i  = r0 + prow;            // output pixel row
    const int yr = i + di - 4;           // y row this thread needs
    const bool rv = (yr >= 0) && (yr < NH);

    // x: always valid. y: invalid rows read a zeroed ws region with stride 0.
    const float* xp = x + ((size_t)(b * NC) * NH + i) * NW + j0;
    const float* yp = rv ? (y + ((size_t)(b * NC) * NH + yr) * NW + j0)
                         : (zpad + j0);
    const size_t ystep = rv ? (size_t)CHST : 0;

    float acc[PATCH][4];
    #pragma unroll
    for (int dj = 0; dj < PATCH; ++dj)
        #pragma unroll
        for (int tt = 0; tt < 4; ++tt) acc[dj][tt] = 0.0f;

    // ---- depth-8 register prefetch pipeline (no LDS, no barriers) ----
    // Queues live entirely in registers: inner loop fully unrolled so every
    // queue index is compile-time static (rule: runtime-indexed arrays spill).
    float4 xq[DEPTH], yq[DEPTH];
    {
        const float* xl = xp;
        const float* yl = yp;
        #pragma unroll
        for (int d = 0; d < DEPTH; ++d) {
            xq[d] = *(const float4*)(xl);  xl += CHST;
            yq[d] = *(const float4*)(yl);  yl += ystep;
        }
    }

    const float* xload = xp + (size_t)DEPTH * CHST;
    const float* yload = yp + (size_t)DEPTH * ystep;

    // main: consume c in [0, NC-DEPTH), prefetch c+DEPTH
    for (int cb = 0; cb < NC - DEPTH; cb += DEPTH) {
        #pragma unroll
        for (int u = 0; u < DEPTH; ++u) {
            const float4 xa = xq[u];
            const float4 ya = yq[u];
            xq[u] = *(const float4*)(xload);  xload += CHST;
            yq[u] = *(const float4*)(yload);  yload += ystep;
            accum(acc, xa, ya);
        }
    }
    // peeled tail: consume the last DEPTH channels, no prefetch
    #pragma unroll
    for (int u = 0; u < DEPTH; ++u)
        accum(acc, xq[u], yq[u]);

    // epilogue: scale, coalesced nontemporal float4 stores (output is
    // write-once, never re-read -> keep it out of L2).
    const float scale = 1.0f / (float)NC;
    float* op = out + (((size_t)b * (PATCH * PATCH) + di * PATCH) * NH + i) * NW + j0;
    #pragma unroll
    for (int dj = 0; dj < PATCH; ++dj) {
        f4_vec o;
        o.x = acc[dj][0] * scale; o.y = acc[dj][1] * scale;
        o.z = acc[dj][2] * scale; o.w = acc[dj][3] * scale;
        __builtin_nontemporal_store(o, (f4_vec*)(op + (size_t)dj * CHST));
    }
}

extern "C" void kernel_launch(void* const* d_in, const int* in_sizes, int n_in,
                              void* d_out, int out_size, void* d_ws, size_t ws_size,
                              hipStream_t stream)
{
    const float* x = (const float*)d_in[0];
    const float* y = (const float*)d_in[1];
    float* out = (float*)d_out;

    // zero page for out-of-range y rows (ws is re-poisoned every launch)
    hipMemsetAsync(d_ws, 0, 1024, stream);

    dim3 grid(3 * NB * (NH / TROWS));   // 768 = exactly 3 blocks/CU resident
    dim3 block(BLOCK_THREADS);          // 192 threads = 3 waves (no barriers used)
    hipLaunchKernelGGL(corr_kernel, grid, block, 0, stream, x, y, out,
                       (const float*)d_ws);
}